// Round 1
// baseline (123.450 us; speedup 1.0000x reference)
//
#include <hip/hip_runtime.h>

#define N_ATOMS 10000
#define N_EDGES 200000
#define EB 64          // edges staged per batch
#define FEAT 40        // 20 radial + 16 angular + 4 species
#define PI_F 3.14159265358979323846f
#define W_F  0.6283185307179586f   // pi/5 rounded to f32

__device__ __forceinline__ int lower_bound_i(const int* __restrict__ a, int n, int v) {
    int lo = 0, hi = n;
    while (lo < hi) {
        int mid = (lo + hi) >> 1;
        if (a[mid] < v) lo = mid + 1; else hi = mid;
    }
    return lo;
}

__global__ __launch_bounds__(128) void sph_expand_kernel(
    const float* __restrict__ R,
    const int*   __restrict__ seg_i,
    const int*   __restrict__ idx_j,
    const int*   __restrict__ species,
    const float* __restrict__ emb,
    float*       __restrict__ out)
{
    __shared__ float feat[EB][FEAT];   // 64*40*4 = 10240 B
    const int atom = blockIdx.x;
    const int tid  = threadIdx.x;

    // ---- decode superpair: thread owns (l, m, n0..n0+1), 8 outputs ----
    // superpair counts: l0: 1*10=10, l1: 3*9=27, l2: 5*8=40, l3: 7*7=49 -> 126
    int m, np_, nl, offm; long base; int stride;
    {
        int t = tid;
        if (t < 10)      { m = 0;                 np_ = t;          nl = 20; offm = 0; base = 0;        stride = 80;  }
        else if (t < 37) { int q = t - 10; m = q / 9; np_ = q - 9*m; nl = 18; offm = 1; base = 800000;  stride = 216; }
        else if (t < 77) { int q = t - 37; m = q / 8; np_ = q - 8*m; nl = 16; offm = 4; base = 2960000; stride = 320; }
        else             { int q = t - 77; m = q / 7; np_ = q - 7*m; nl = 14; offm = 9; base = 6160000; stride = 392; }
    }
    const int n0   = 2 * np_;
    const int aidx = 20 + offm + m;
    const bool active = (tid < 126);

    float a0x=0.f, a0y=0.f, a0z=0.f, a0w=0.f;
    float a1x=0.f, a1y=0.f, a1z=0.f, a1w=0.f;

    const int start = lower_bound_i(seg_i, N_EDGES, atom);
    const int end   = lower_bound_i(seg_i, N_EDGES, atom + 1);

    for (int e0 = start; e0 < end; e0 += EB) {
        const int cnt = min(EB, end - e0);
        __syncthreads();   // protect LDS from previous batch's readers
        if (tid < cnt) {
            const int g = e0 + tid;
            const float x = R[3*g + 0];
            const float y = R[3*g + 1];
            const float z = R[3*g + 2];
            const float r   = sqrtf(x*x + y*y + z*z);
            const float inv = 1.0f / (r + 1e-12f);
            const float ux = x*inv, uy = y*inv, uz = z*inv;
            const float rc = fminf(r, 5.0f);
            const float fc = 0.5f * (cosf((PI_F * rc) / 5.0f) + 1.0f);

            float rb[20];
            #pragma unroll
            for (int k = 0; k < 20; ++k) {
                const float fk = (float)(k + 1) * W_F;   // matches _FREQS*(pi/5)
                rb[k] = sinf(fk * r) * fc;               // then * r
            }

            const float x2 = ux*ux, y2 = uy*uy, z2 = uz*uz;
            const float c1 = 0.4886025119029199f;
            const float c2 = 1.0925484305920792f;
            float an[16];
            an[0]  = 0.28209479177387814f;
            an[1]  = c1 * uy;
            an[2]  = c1 * uz;
            an[3]  = c1 * ux;
            an[4]  = c2 * ux * uy;
            an[5]  = c2 * uy * uz;
            an[6]  = 0.31539156525252005f * (3.0f*z2 - 1.0f);
            an[7]  = c2 * ux * uz;
            an[8]  = 0.5462742152960396f * (x2 - y2);
            an[9]  = 0.5900435899266435f * uy * (3.0f*x2 - y2);
            an[10] = 2.890611442640554f  * ux * uy * uz;
            an[11] = 0.4570457994644658f * uy * (5.0f*z2 - 1.0f);
            an[12] = 0.3731763325901154f * uz * (5.0f*z2 - 3.0f);
            an[13] = 0.4570457994644658f * ux * (5.0f*z2 - 1.0f);
            an[14] = 1.445305721320277f  * uz * (x2 - y2);
            an[15] = 0.5900435899266435f * ux * (x2 - 3.0f*y2);

            const int jj = idx_j[g];
            const int sidx = species[jj];
            const float4 spv = *(const float4*)&emb[4 * sidx];

            float4* row = (float4*)&feat[tid][0];
            row[0] = float4{rb[0],  rb[1],  rb[2],  rb[3]};
            row[1] = float4{rb[4],  rb[5],  rb[6],  rb[7]};
            row[2] = float4{rb[8],  rb[9],  rb[10], rb[11]};
            row[3] = float4{rb[12], rb[13], rb[14], rb[15]};
            row[4] = float4{rb[16], rb[17], rb[18], rb[19]};
            row[5] = float4{an[0],  an[1],  an[2],  an[3]};
            row[6] = float4{an[4],  an[5],  an[6],  an[7]};
            row[7] = float4{an[8],  an[9],  an[10], an[11]};
            row[8] = float4{an[12], an[13], an[14], an[15]};
            row[9] = spv;
        }
        __syncthreads();
        if (active) {
            for (int s = 0; s < cnt; ++s) {
                const float* f = &feat[s][0];
                const float2 rv  = *(const float2*)(f + n0);
                const float  av  = f[aidx];
                const float4 spv = *(const float4*)(f + 36);
                const float p0 = rv.x * av;
                const float p1 = rv.y * av;
                a0x += p0 * spv.x; a0y += p0 * spv.y; a0z += p0 * spv.z; a0w += p0 * spv.w;
                a1x += p1 * spv.x; a1y += p1 * spv.y; a1z += p1 * spv.z; a1w += p1 * spv.w;
            }
        }
    }

    if (active) {
        const size_t o = (size_t)base + (size_t)atom * (size_t)stride + (size_t)(m * nl + n0) * 4;
        *(float4*)&out[o]     = float4{a0x, a0y, a0z, a0w};
        *(float4*)&out[o + 4] = float4{a1x, a1y, a1z, a1w};
    }
}

extern "C" void kernel_launch(void* const* d_in, const int* in_sizes, int n_in,
                              void* d_out, int out_size, void* d_ws, size_t ws_size,
                              hipStream_t stream) {
    const float* R    = (const float*)d_in[0];
    const int*   i_   = (const int*)  d_in[1];
    const int*   j_   = (const int*)  d_in[2];
    const int*   sp   = (const int*)  d_in[3];
    const float* emb  = (const float*)d_in[4];
    float* out = (float*)d_out;
    sph_expand_kernel<<<N_ATOMS, 128, 0, stream>>>(R, i_, j_, sp, emb, out);
}

// Round 2
// 91.462 us; speedup vs baseline: 1.3497x; 1.3497x over previous
//
#include <hip/hip_runtime.h>

#define N_ATOMS 10000
#define N_EDGES 200000
#define EB 64          // edges staged per batch
#define FEAT 40        // 20 radial + 16 angular + 4 species
#define PI_F 3.14159265358979323846f
#define W_F  0.6283185307179586f   // pi/5 in f32

// ---- kernel A: precompute segment starts (starts[a] = lower_bound(seg_i, a)) ----
__global__ __launch_bounds__(256) void seg_starts_kernel(
    const int* __restrict__ seg_i, int* __restrict__ starts)
{
    const int a = blockIdx.x * blockDim.x + threadIdx.x;
    if (a > N_ATOMS) return;
    int lo = 0, hi = N_EDGES;
    while (lo < hi) {
        int mid = (lo + hi) >> 1;
        if (seg_i[mid] < a) lo = mid + 1; else hi = mid;
    }
    starts[a] = lo;
}

// ---- kernel B: one block per atom ----
__global__ __launch_bounds__(128) void sph_expand_kernel(
    const float* __restrict__ R,
    const int*   __restrict__ starts,
    const int*   __restrict__ idx_j,
    const int*   __restrict__ species,
    const float* __restrict__ emb,
    float*       __restrict__ out)
{
    __shared__ float feat[EB][FEAT];   // 10240 B
    const int atom = blockIdx.x;
    const int tid  = threadIdx.x;

    // superpair decode: thread owns (l, m, n0..n0+1) -> 8 outputs
    // counts: l0 1*10=10, l1 3*9=27, l2 5*8=40, l3 7*7=49 -> 126 active
    int m, np_, nl, offm; long base; int stride;
    {
        int t = tid;
        if (t < 10)      { m = 0;                 np_ = t;          nl = 20; offm = 0; base = 0;        stride = 80;  }
        else if (t < 37) { int q = t - 10; m = q / 9; np_ = q - 9*m; nl = 18; offm = 1; base = 800000;  stride = 216; }
        else if (t < 77) { int q = t - 37; m = q / 8; np_ = q - 8*m; nl = 16; offm = 4; base = 2960000; stride = 320; }
        else             { int q = t - 77; m = q / 7; np_ = q - 7*m; nl = 14; offm = 9; base = 6160000; stride = 392; }
    }
    const int n0   = 2 * np_;
    const int aidx = 20 + offm + m;
    const bool active = (tid < 126);

    float a0x=0.f, a0y=0.f, a0z=0.f, a0w=0.f;
    float a1x=0.f, a1y=0.f, a1z=0.f, a1w=0.f;

    const int start = starts[atom];
    const int end   = starts[atom + 1];

    for (int e0 = start; e0 < end; e0 += EB) {
        const int cnt = min(EB, end - e0);
        __syncthreads();
        if (tid < cnt) {
            const int g = e0 + tid;
            const int jj = idx_j[g];                 // issue gathers early
            const float x = R[3*g + 0];
            const float y = R[3*g + 1];
            const float z = R[3*g + 2];
            const int sidx = species[jj];
            const float r   = sqrtf(x*x + y*y + z*z);
            const float inv = 1.0f / (r + 1e-12f);
            const float ux = x*inv, uy = y*inv, uz = z*inv;
            const float4 spv = *(const float4*)&emb[4 * sidx];

            // one sin + one cos; harmonics via Chebyshev recurrence
            const float t1 = W_F * r;
            const float s1 = sinf(t1);
            const float c1 = cosf(t1);
            const float fc = (r < 5.0f) ? (0.5f * (c1 + 1.0f)) : 0.0f;
            const float c2x = 2.0f * c1;

            float rb[20];
            {
                float sk_2 = 0.0f, sk_1 = s1;
                rb[0] = s1 * fc;
                #pragma unroll
                for (int k = 1; k < 20; ++k) {
                    const float sk = c2x * sk_1 - sk_2;
                    rb[k] = sk * fc;
                    sk_2 = sk_1; sk_1 = sk;
                }
            }

            const float x2 = ux*ux, y2 = uy*uy, z2 = uz*uz;
            const float c1a = 0.4886025119029199f;
            const float c2a = 1.0925484305920792f;
            float an[16];
            an[0]  = 0.28209479177387814f;
            an[1]  = c1a * uy;
            an[2]  = c1a * uz;
            an[3]  = c1a * ux;
            an[4]  = c2a * ux * uy;
            an[5]  = c2a * uy * uz;
            an[6]  = 0.31539156525252005f * (3.0f*z2 - 1.0f);
            an[7]  = c2a * ux * uz;
            an[8]  = 0.5462742152960396f * (x2 - y2);
            an[9]  = 0.5900435899266435f * uy * (3.0f*x2 - y2);
            an[10] = 2.890611442640554f  * ux * uy * uz;
            an[11] = 0.4570457994644658f * uy * (5.0f*z2 - 1.0f);
            an[12] = 0.3731763325901154f * uz * (5.0f*z2 - 3.0f);
            an[13] = 0.4570457994644658f * ux * (5.0f*z2 - 1.0f);
            an[14] = 1.445305721320277f  * uz * (x2 - y2);
            an[15] = 0.5900435899266435f * ux * (x2 - 3.0f*y2);

            float4* row = (float4*)&feat[tid][0];
            row[0] = float4{rb[0],  rb[1],  rb[2],  rb[3]};
            row[1] = float4{rb[4],  rb[5],  rb[6],  rb[7]};
            row[2] = float4{rb[8],  rb[9],  rb[10], rb[11]};
            row[3] = float4{rb[12], rb[13], rb[14], rb[15]};
            row[4] = float4{rb[16], rb[17], rb[18], rb[19]};
            row[5] = float4{an[0],  an[1],  an[2],  an[3]};
            row[6] = float4{an[4],  an[5],  an[6],  an[7]};
            row[7] = float4{an[8],  an[9],  an[10], an[11]};
            row[8] = float4{an[12], an[13], an[14], an[15]};
            row[9] = spv;
        }
        __syncthreads();
        if (active) {
            for (int s = 0; s < cnt; ++s) {
                const float* f = &feat[s][0];
                const float2 rv  = *(const float2*)(f + n0);
                const float  av  = f[aidx];
                const float4 spv = *(const float4*)(f + 36);
                const float p0 = rv.x * av;
                const float p1 = rv.y * av;
                a0x += p0 * spv.x; a0y += p0 * spv.y; a0z += p0 * spv.z; a0w += p0 * spv.w;
                a1x += p1 * spv.x; a1y += p1 * spv.y; a1z += p1 * spv.z; a1w += p1 * spv.w;
            }
        }
    }

    if (active) {
        const size_t o = (size_t)base + (size_t)atom * (size_t)stride + (size_t)(m * nl + n0) * 4;
        *(float4*)&out[o]     = float4{a0x, a0y, a0z, a0w};
        *(float4*)&out[o + 4] = float4{a1x, a1y, a1z, a1w};
    }
}

extern "C" void kernel_launch(void* const* d_in, const int* in_sizes, int n_in,
                              void* d_out, int out_size, void* d_ws, size_t ws_size,
                              hipStream_t stream) {
    const float* R    = (const float*)d_in[0];
    const int*   i_   = (const int*)  d_in[1];
    const int*   j_   = (const int*)  d_in[2];
    const int*   sp   = (const int*)  d_in[3];
    const float* emb  = (const float*)d_in[4];
    float* out = (float*)d_out;
    int*   starts = (int*)d_ws;   // 10001 ints

    seg_starts_kernel<<<(N_ATOMS + 256) / 256, 256, 0, stream>>>(i_, starts);
    sph_expand_kernel<<<N_ATOMS, 128, 0, stream>>>(R, starts, j_, sp, emb, out);
}